// Round 4
// baseline (519.519 us; speedup 1.0000x reference)
//
#include <hip/hip_runtime.h>
#include <cstdint>

#define OWD 126
#define MTOT 15876   // 126*126

typedef short bf16x8 __attribute__((ext_vector_type(8)));
typedef float f32x4  __attribute__((ext_vector_type(4)));

#define BT_ELEMS  (16u * 128u * 1152u)                 // 2,359,296 bf16
#define XBF_ELEMS (16u * 128u * 128u * 128u)           // 33,554,432 bf16
#define WS_NEEDED ((size_t)(BT_ELEMS + XBF_ELEMS) * 2) // ~71.8 MB

__device__ __forceinline__ uint16_t f2bf(float f) {
    union { float f; uint32_t u; } v;
    v.f = f;
    uint32_t u = v.u;
    return (uint16_t)((u + 0x7FFFu + ((u >> 16) & 1u)) >> 16);
}

__device__ __forceinline__ uint32_t pk2(float a, float b) {
    return (uint32_t)f2bf(a) | ((uint32_t)f2bf(b) << 16);
}

// ---------------------------------------------------------------------------
// Prep 1: kernel [16][9][128 c][128 n] fp32 -> Bt [16][128 n][1152 k] bf16
// ---------------------------------------------------------------------------
__global__ __launch_bounds__(256) void kprep(const float* __restrict__ Kin,
                                             uint16_t* __restrict__ Bt) {
    const int rs = blockIdx.x;   // 0..8
    const int b  = blockIdx.y;   // 0..15
    const int t  = threadIdx.x;
    const int n  = t & 127;
    const int og = t >> 7;

    const float* src = Kin + (((size_t)b * 9 + rs) << 14);
    uint16_t*    dst = Bt + ((size_t)b * 128 + n) * 1152 + rs * 128;

#pragma unroll
    for (int o = 0; o < 8; ++o) {
        const int oct = og * 8 + o;
        const float* s0 = src + (oct * 8) * 128 + n;
        uint4 p;
        p.x = pk2(s0[0 * 128], s0[1 * 128]);
        p.y = pk2(s0[2 * 128], s0[3 * 128]);
        p.z = pk2(s0[4 * 128], s0[5 * 128]);
        p.w = pk2(s0[6 * 128], s0[7 * 128]);
        *(uint4*)(dst + oct * 8) = p;
    }
}

// ---------------------------------------------------------------------------
// Prep 2: X fp32 NHWC -> bf16 NHWC (same layout), 8 elems/thread
// ---------------------------------------------------------------------------
__global__ __launch_bounds__(256) void xprep(const float* __restrict__ X,
                                             uint16_t* __restrict__ Xbf) {
    const size_t i = ((size_t)blockIdx.x * 256 + threadIdx.x) * 8;
    const float4 a = *(const float4*)(X + i);
    const float4 b = *(const float4*)(X + i + 4);
    uint4 p;
    p.x = pk2(a.x, a.y);
    p.y = pk2(a.z, a.w);
    p.z = pk2(b.x, b.y);
    p.w = pk2(b.z, b.w);
    *(uint4*)(Xbf + i) = p;
}

// ---------------------------------------------------------------------------
// Main: BARRIER-FREE implicit-GEMM conv.
// Both MFMA fragments are 16 contiguous bytes in the prepared layouts, so
// each wave loads fragments directly from global (L1/L2-hot) into VGPRs --
// no LDS, no __syncthreads, double-buffered 1-step register prefetch.
// K steps: s = 0..35, each K=32: rs = s>>2, c-offset = (s&3)*32.
//   A-frag af[i]: m = mtile*128+wm+i*16+(lane&15), k-octet = quad*8
//   B-frag bf[j]: n = wn+j*16+(lane&15),          k-octet = quad*8
// ---------------------------------------------------------------------------
__global__ __launch_bounds__(256) void conv_mfma_b(const uint16_t* __restrict__ Xbf,
                                                   const uint16_t* __restrict__ Bt,
                                                   float* __restrict__ Out) {
    const int mtile = blockIdx.x;  // 0..124
    const int b     = blockIdx.y;  // 0..15
    const int tid   = threadIdx.x;
    const int lane  = tid & 63;
    const int wave  = tid >> 6;
    const int wm    = (wave & 1) << 6;
    const int wn    = (wave >> 1) << 6;
    const int l15   = lane & 15;
    const int quad  = lane >> 4;

    // per-lane fragment row pointers
    const uint16_t* Ap[4];
#pragma unroll
    for (int i = 0; i < 4; ++i) {
        int m = mtile * 128 + wm + i * 16 + l15;
        if (m >= MTOT) m = MTOT - 1;
        const int oh = m / OWD, ow = m - oh * OWD;
        Ap[i] = Xbf + (((size_t)b * 128 + oh) * 128 + ow) * 128 + quad * 8;
    }
    const uint16_t* Bp[4];
#pragma unroll
    for (int j = 0; j < 4; ++j) {
        const int n = wn + j * 16 + l15;
        Bp[j] = Bt + ((size_t)b * 128 + n) * 1152 + quad * 8;
    }

    f32x4 acc[4][4];
#pragma unroll
    for (int i = 0; i < 4; ++i)
#pragma unroll
        for (int j = 0; j < 4; ++j)
            acc[i][j] = (f32x4){0.f, 0.f, 0.f, 0.f};

#define LOADS(s, AF, BF)                                                      \
    do {                                                                      \
        const int rs_ = (s) >> 2;                                             \
        const int r_  = rs_ / 3;                                              \
        const int sc_ = rs_ - r_ * 3;                                         \
        const int ao_ = (r_ * 128 + sc_) * 128 + ((s) & 3) * 32;              \
        const int bo_ = (s) * 32;                                             \
        _Pragma("unroll") for (int i_ = 0; i_ < 4; ++i_)                      \
            AF[i_] = *(const bf16x8*)(Ap[i_] + ao_);                          \
        _Pragma("unroll") for (int j_ = 0; j_ < 4; ++j_)                      \
            BF[j_] = *(const bf16x8*)(Bp[j_] + bo_);                          \
    } while (0)

#define MF(AF, BF)                                                            \
    do {                                                                      \
        _Pragma("unroll") for (int i_ = 0; i_ < 4; ++i_)                      \
        _Pragma("unroll") for (int j_ = 0; j_ < 4; ++j_)                      \
            acc[i_][j_] = __builtin_amdgcn_mfma_f32_16x16x32_bf16(            \
                AF[i_], BF[j_], acc[i_][j_], 0, 0, 0);                        \
    } while (0)

    bf16x8 A0[4], B0[4], A1[4], B1[4];
    LOADS(0, A0, B0);
#pragma unroll
    for (int sp = 0; sp < 17; ++sp) {
        LOADS(2 * sp + 1, A1, B1);   // prefetch odd step
        MF(A0, B0);                  // compute even step 2*sp
        LOADS(2 * sp + 2, A0, B0);   // prefetch next even step
        MF(A1, B1);                  // compute odd step 2*sp+1
    }
    LOADS(35, A1, B1);
    MF(A0, B0);   // s = 34
    MF(A1, B1);   // s = 35

#undef LOADS
#undef MF

    // epilogue: D row = quad*4+reg, col = lane&15 (verified)
#pragma unroll
    for (int i = 0; i < 4; ++i) {
#pragma unroll
        for (int rr = 0; rr < 4; ++rr) {
            const int mrow = mtile * 128 + wm + i * 16 + quad * 4 + rr;
            if (mrow < MTOT) {
                const int oh2 = mrow / OWD;
                const int ow2 = mrow - oh2 * OWD;
                float* op = Out + (((size_t)b * OWD + oh2) * OWD + ow2) * 128 + wn + l15;
#pragma unroll
                for (int j = 0; j < 4; ++j)
                    op[j * 16] = acc[i][j][rr];
            }
        }
    }
}

// ---------------------------------------------------------------------------
// Fallback (ws too small): round-1 kernel, fp32 X with in-kernel cvt.
// ---------------------------------------------------------------------------
__global__ __launch_bounds__(256) void conv_mfma(const float* __restrict__ X,
                                                 const uint16_t* __restrict__ Bt,
                                                 float* __restrict__ Out) {
    __shared__ __align__(16) uint16_t lA[128 * 64];
    __shared__ __align__(16) uint16_t lB[128 * 64];

    const int mtile = blockIdx.x;
    const int b     = blockIdx.y;
    const int tid   = threadIdx.x;
    const int lane  = tid & 63;
    const int wave  = tid >> 6;
    const int wm    = (wave & 1) << 6;
    const int wn    = (wave >> 1) << 6;
    const int l15   = lane & 15;
    const int quad  = lane >> 4;

    const int srow  = tid >> 1;
    const int shalf = tid & 1;

    int m = mtile * 128 + srow;
    if (m >= MTOT) m = MTOT - 1;
    const int oh = m / OWD;
    const int ow = m - oh * OWD;
    const float*    Xb = X + (((size_t)b * 128 + oh) * 128 + ow) * 128;
    const uint16_t* Bb = Bt + ((size_t)b * 128 + srow) * 1152 + shalf * 32;

    f32x4 acc[4][4];
#pragma unroll
    for (int i = 0; i < 4; ++i)
#pragma unroll
        for (int j = 0; j < 4; ++j)
            acc[i][j] = (f32x4){0.f, 0.f, 0.f, 0.f};

    for (int chunk = 0; chunk < 18; ++chunk) {
        const int rs = chunk >> 1;
        const int c0 = (chunk & 1) << 6;
        const int r  = rs / 3;
        const int s  = rs - r * 3;

        __syncthreads();
        {
            const float4* src = (const float4*)(Xb + (r * 128 + s) * 128 + c0 + shalf * 32);
            float4 v[8];
#pragma unroll
            for (int i = 0; i < 8; ++i) v[i] = src[i];
#pragma unroll
            for (int i = 0; i < 4; ++i) {
                uint4 p;
                p.x = pk2(v[2 * i].x, v[2 * i].y);
                p.y = pk2(v[2 * i].z, v[2 * i].w);
                p.z = pk2(v[2 * i + 1].x, v[2 * i + 1].y);
                p.w = pk2(v[2 * i + 1].z, v[2 * i + 1].w);
                const int ci = (shalf * 4 + i) ^ (srow & 7);
                *(uint4*)&lA[srow * 64 + ci * 8] = p;
            }
        }
        {
            const uint4* bsrc = (const uint4*)(Bb + rs * 128 + c0);
#pragma unroll
            for (int i = 0; i < 4; ++i) {
                const uint4 p = bsrc[i];
                const int ci = (shalf * 4 + i) ^ (srow & 7);
                *(uint4*)&lB[srow * 64 + ci * 8] = p;
            }
        }
        __syncthreads();

#pragma unroll
        for (int ksub = 0; ksub < 2; ++ksub) {
            bf16x8 af[4], bfr[4];
#pragma unroll
            for (int i = 0; i < 4; ++i) {
                const int row = wm + i * 16 + l15;
                const int ci  = (ksub * 4 + quad) ^ (row & 7);
                af[i] = *(const bf16x8*)&lA[row * 64 + ci * 8];
            }
#pragma unroll
            for (int j = 0; j < 4; ++j) {
                const int row = wn + j * 16 + l15;
                const int ci  = (ksub * 4 + quad) ^ (row & 7);
                bfr[j] = *(const bf16x8*)&lB[row * 64 + ci * 8];
            }
#pragma unroll
            for (int i = 0; i < 4; ++i)
#pragma unroll
                for (int j = 0; j < 4; ++j)
                    acc[i][j] = __builtin_amdgcn_mfma_f32_16x16x32_bf16(
                        af[i], bfr[j], acc[i][j], 0, 0, 0);
        }
    }

#pragma unroll
    for (int i = 0; i < 4; ++i) {
#pragma unroll
        for (int rr = 0; rr < 4; ++rr) {
            const int mrow = mtile * 128 + wm + i * 16 + quad * 4 + rr;
            if (mrow < MTOT) {
                const int oh2 = mrow / OWD;
                const int ow2 = mrow - oh2 * OWD;
                float* op = Out + (((size_t)b * OWD + oh2) * OWD + ow2) * 128 + wn + l15;
#pragma unroll
                for (int j = 0; j < 4; ++j)
                    op[j * 16] = acc[i][j][rr];
            }
        }
    }
}

extern "C" void kernel_launch(void* const* d_in, const int* in_sizes, int n_in,
                              void* d_out, int out_size, void* d_ws, size_t ws_size,
                              hipStream_t stream) {
    const float* X   = (const float*)d_in[0];   // [16,128,128,128]
    const float* Kin = (const float*)d_in[1];   // [16,3,3,128,128]
    float*       Out = (float*)d_out;           // [16,126,126,128]
    uint16_t*    Bt  = (uint16_t*)d_ws;         // bf16 [16][128][1152]
    uint16_t*    Xbf = Bt + BT_ELEMS;           // bf16 [16][128][128][128]

    kprep<<<dim3(9, 16), 256, 0, stream>>>(Kin, Bt);
    if (ws_size >= WS_NEEDED) {
        xprep<<<XBF_ELEMS / (256 * 8), 256, 0, stream>>>(X, Xbf);
        conv_mfma_b<<<dim3(125, 16), 256, 0, stream>>>(Xbf, Bt, Out);
    } else {
        conv_mfma<<<dim3(125, 16), 256, 0, stream>>>(X, Bt, Out);
    }
}